// Round 3
// baseline (930.937 us; speedup 1.0000x reference)
//
#include <hip/hip_runtime.h>

#define NEG_SLOPE 0.2f

// ---------------------------------------------------------------- CSR build
__global__ void zero_int_kernel(int* __restrict__ p, int n) {
  int i = blockIdx.x * blockDim.x + threadIdx.x;
  if (i < n) p[i] = 0;
}

__global__ void count_kernel(const int* __restrict__ ei, int E, int N,
                             int* __restrict__ cnt) {
  int e = blockIdx.x * blockDim.x + threadIdx.x;
  int tot = E + N;
  if (e >= tot) return;
  int dst = (e < E) ? ei[E + e] : (e - E);
  atomicAdd(&cnt[dst], 1);
}

// 1024 threads, one block. Per-thread serial chunk + shuffle block-scan.
__global__ __launch_bounds__(1024) void scan_kernel(const int* __restrict__ cnt,
                                                    int* __restrict__ row_ptr,
                                                    int* __restrict__ cursor,
                                                    int N) {
  int t = threadIdx.x;
  int CH = (N + 1023) >> 10;
  int b = t * CH; if (b > N) b = N;
  int e = b + CH; if (e > N) e = N;
  int sum = 0;
  for (int i = b; i < e; ++i) sum += cnt[i];
  int lane = t & 63, wid = t >> 6;
  int v = sum;
#pragma unroll
  for (int off = 1; off < 64; off <<= 1) {
    int u = __shfl_up(v, off, 64);
    if (lane >= off) v += u;
  }
  __shared__ int wsum[16];
  __shared__ int wpre[16];
  if (lane == 63) wsum[wid] = v;
  __syncthreads();
  if (t < 16) {
    int wv = wsum[t];
#pragma unroll
    for (int off = 1; off < 16; off <<= 1) {
      int u = __shfl_up(wv, off, 16);
      if (t >= off) wv += u;
    }
    wpre[t] = wv - wsum[t];
  }
  __syncthreads();
  int run = wpre[wid] + (v - sum);
  for (int i = b; i < e; ++i) {
    int c = cnt[i];
    row_ptr[i] = run;
    cursor[i] = run;
    run += c;
  }
  if (t == 1023) row_ptr[N] = run;
}

__global__ void fill_kernel(const int* __restrict__ ei, int E, int N,
                            int* __restrict__ cursor, int* __restrict__ col_src) {
  int e = blockIdx.x * blockDim.x + threadIdx.x;
  int tot = E + N;
  if (e >= tot) return;
  int src, dst;
  if (e < E) { src = ei[e]; dst = ei[E + e]; } else { src = e - E; dst = e - E; }
  int pos = atomicAdd(&cursor[dst], 1);
  col_src[pos] = src;
}

// ---------------------------------------------------------------- SGEMM fp32
// Y[M,N] = X[M,K] @ W[K,N].  256 threads, BK=16, double-buffered LDS,
// one barrier per K-step; global loads overlap compute.
template <int BM, int BN>
__global__ __launch_bounds__(256) void sgemm_kernel(const float* __restrict__ X,
                                                    const float* __restrict__ W,
                                                    float* __restrict__ Y,
                                                    int M, int N, int K) {
  constexpr int BK = 16;
  constexpr int LDA = BM + 4;
  constexpr int HM = BM / 2;
  constexpr int JH = (BN == 128) ? 2 : 1;
  constexpr int HN = BN / 2;
  constexpr int nA4 = BM * BK / 1024;   // float4/thread for A (2 when BM=128)
  constexpr int nB4 = BK * BN / 1024;   // 2 when BN=128, 1 when BN=64
  __shared__ float As[2][BK][LDA];
  __shared__ float Bs[2][BK][BN];
  int tid = threadIdx.x;
  int br = blockIdx.y * BM, bc = blockIdx.x * BN;
  int trow = tid >> 4, tcol = tid & 15;
  float acc[2][JH][4][4] = {};
  float4 ra[nA4], rb[nB4];

  auto loadA = [&](int k0) {
#pragma unroll
    for (int i = 0; i < nA4; ++i) {
      int f = tid + i * 256;
      int row = f >> 2;
      int kq = (f & 3) * 4;
      int gm = br + row;
      ra[i] = (gm < M) ? *(const float4*)&X[(size_t)gm * K + k0 + kq]
                       : make_float4(0.f, 0.f, 0.f, 0.f);
    }
  };
  auto loadB = [&](int k0) {
#pragma unroll
    for (int i = 0; i < nB4; ++i) {
      int f = tid + i * 256;
      int kk = f / (BN / 4);
      int nq = (f % (BN / 4)) * 4;
      rb[i] = *(const float4*)&W[(size_t)(k0 + kk) * N + bc + nq];
    }
  };
  auto storeTiles = [&](int buf) {
#pragma unroll
    for (int i = 0; i < nA4; ++i) {
      int f = tid + i * 256;
      int row = f >> 2;
      int kq = (f & 3) * 4;
      As[buf][kq + 0][row] = ra[i].x; As[buf][kq + 1][row] = ra[i].y;
      As[buf][kq + 2][row] = ra[i].z; As[buf][kq + 3][row] = ra[i].w;
    }
#pragma unroll
    for (int i = 0; i < nB4; ++i) {
      int f = tid + i * 256;
      int kk = f / (BN / 4);
      int nq = (f % (BN / 4)) * 4;
      *(float4*)&Bs[buf][kk][nq] = rb[i];
    }
  };

  loadA(0); loadB(0);
  storeTiles(0);
  __syncthreads();

  int nst = K / BK;
  for (int s = 0; s < nst; ++s) {
    int cur = s & 1;
    if (s + 1 < nst) { loadA((s + 1) * BK); loadB((s + 1) * BK); }
#pragma unroll
    for (int kk = 0; kk < BK; ++kk) {
      float ar[2][4], brg[JH][4];
      *(float4*)&ar[0][0] = *(const float4*)&As[cur][kk][trow * 4];
      *(float4*)&ar[1][0] = *(const float4*)&As[cur][kk][trow * 4 + HM];
      *(float4*)&brg[0][0] = *(const float4*)&Bs[cur][kk][tcol * 4];
      if constexpr (JH == 2)
        *(float4*)&brg[1][0] = *(const float4*)&Bs[cur][kk][tcol * 4 + HN];
#pragma unroll
      for (int ih = 0; ih < 2; ++ih)
#pragma unroll
        for (int jh = 0; jh < JH; ++jh)
#pragma unroll
          for (int i = 0; i < 4; ++i)
#pragma unroll
            for (int j = 0; j < 4; ++j)
              acc[ih][jh][i][j] += ar[ih][i] * brg[jh][j];
    }
    if (s + 1 < nst) storeTiles(1 - cur);
    __syncthreads();
  }

#pragma unroll
  for (int ih = 0; ih < 2; ++ih)
#pragma unroll
    for (int i = 0; i < 4; ++i) {
      int gm = br + ih * HM + trow * 4 + i;
      if (gm >= M) continue;
#pragma unroll
      for (int jh = 0; jh < JH; ++jh) {
        float4 o = make_float4(acc[ih][jh][i][0], acc[ih][jh][i][1],
                               acc[ih][jh][i][2], acc[ih][jh][i][3]);
        int gn = bc + (JH == 2 ? jh * HN : 0) + tcol * 4;
        *(float4*)&Y[(size_t)gm * N + gn] = o;
      }
    }
}

// ------------------------------------------------- per-node alpha_s/alpha_d
template <int H, int C>
__global__ void alpha_kernel(const float* __restrict__ h,
                             const float* __restrict__ a_s,
                             const float* __restrict__ a_d,
                             float* __restrict__ out_s,
                             float* __restrict__ out_d, int N) {
  constexpr int HC = H * C;
  constexpr int PER = HC / 64;
  constexpr int SEG = C / PER;
  int lane = threadIdx.x & 63;
  int node = (blockIdx.x * blockDim.x + threadIdx.x) >> 6;
  if (node >= N) return;
  int cbase = lane * PER;
  const float* row = h + (size_t)node * HC + cbase;
  float ss, dd;
  if constexpr (PER == 4) {
    float4 v = *(const float4*)row;
    float4 s4 = *(const float4*)(a_s + cbase);
    float4 d4 = *(const float4*)(a_d + cbase);
    ss = v.x * s4.x + v.y * s4.y + v.z * s4.z + v.w * s4.w;
    dd = v.x * d4.x + v.y * d4.y + v.z * d4.z + v.w * d4.w;
  } else {
    float v = row[0];
    ss = v * a_s[cbase];
    dd = v * a_d[cbase];
  }
#pragma unroll
  for (int off = SEG >> 1; off >= 1; off >>= 1) {
    ss += __shfl_xor(ss, off, 64);
    dd += __shfl_xor(dd, off, 64);
  }
  if ((lane % SEG) == 0) {
    int head = lane / SEG;
    out_s[(size_t)node * H + head] = ss;
    out_d[(size_t)node * H + head] = dd;
  }
}

// ------------------------------- segment softmax + mean-aggregate + bias(+relu)
// One wave per dst node. No max-pass (|e| small; softmax identical).
template <int H, int C, bool RELU>
__global__ void aggregate_kernel(const float* __restrict__ h,
                                 const float* __restrict__ as_,
                                 const float* __restrict__ ad_,
                                 const int* __restrict__ row_ptr,
                                 const int* __restrict__ col_src,
                                 const float* __restrict__ bias,
                                 float* __restrict__ out, int N) {
  constexpr int HC = H * C;
  constexpr int PER = HC / 64;
  int lane = threadIdx.x & 63;
  int node = (blockIdx.x * blockDim.x + threadIdx.x) >> 6;
  if (node >= N) return;
  int beg = row_ptr[node], end = row_ptr[node + 1];
  int deg = end - beg;
  float inv_deg = 1.f / (float)deg;
  int myhead = (lane * PER) / C;
  float facc[PER] = {};

  if constexpr (H == 4) {
    float4 adv4 = *(const float4*)(ad_ + (size_t)node * 4);
    if (deg <= 16) {
      // lane = head_w*16 + e_w holds weight of edge e_w for head head_w
      int head_w = lane >> 4, e_w = lane & 15;
      float q = 0.f; int s_w = 0;
      if (e_w < deg) {
        s_w = col_src[beg + e_w];
        float4 a4 = *(const float4*)(as_ + (size_t)s_w * 4);
        float av = head_w == 0 ? a4.x : head_w == 1 ? a4.y : head_w == 2 ? a4.z : a4.w;
        float dv = head_w == 0 ? adv4.x : head_w == 1 ? adv4.y : head_w == 2 ? adv4.z : adv4.w;
        float e = av + dv;
        e = (e > 0.f) ? e : NEG_SLOPE * e;
        q = __expf(e);
      }
      // segmented (16-lane) sum -> per-head denom
      float dn = q;
      dn += __shfl_xor(dn, 1, 64);
      dn += __shfl_xor(dn, 2, 64);
      dn += __shfl_xor(dn, 4, 64);
      dn += __shfl_xor(dn, 8, 64);
      float qs = q * (1.f / dn) * inv_deg;
      int base = myhead << 4;   // consumer's head group
      for (int i = 0; i < deg; ++i) {
        int srcn = __shfl(s_w, base + i, 64);
        float w = __shfl(qs, base + i, 64);
        float4 v = *(const float4*)(h + (size_t)srcn * HC + lane * 4);
        facc[0] += v.x * w; facc[1] += v.y * w;
        facc[2] += v.z * w; facc[3] += v.w * w;
      }
    } else if (deg <= 64) {
      float p0 = 0.f, p1 = 0.f, p2 = 0.f, p3 = 0.f; int s_w = 0;
      if (lane < deg) {
        s_w = col_src[beg + lane];
        float4 a4 = *(const float4*)(as_ + (size_t)s_w * 4);
        float e0 = a4.x + adv4.x; e0 = e0 > 0.f ? e0 : NEG_SLOPE * e0; p0 = __expf(e0);
        float e1 = a4.y + adv4.y; e1 = e1 > 0.f ? e1 : NEG_SLOPE * e1; p1 = __expf(e1);
        float e2 = a4.z + adv4.z; e2 = e2 > 0.f ? e2 : NEG_SLOPE * e2; p2 = __expf(e2);
        float e3 = a4.w + adv4.w; e3 = e3 > 0.f ? e3 : NEG_SLOPE * e3; p3 = __expf(e3);
      }
      float d0 = p0, d1 = p1, d2 = p2, d3 = p3;
#pragma unroll
      for (int off = 32; off >= 1; off >>= 1) {
        d0 += __shfl_xor(d0, off, 64);
        d1 += __shfl_xor(d1, off, 64);
        d2 += __shfl_xor(d2, off, 64);
        d3 += __shfl_xor(d3, off, 64);
      }
      p0 *= (1.f / d0) * inv_deg;
      p1 *= (1.f / d1) * inv_deg;
      p2 *= (1.f / d2) * inv_deg;
      p3 *= (1.f / d3) * inv_deg;
      for (int i = 0; i < deg; ++i) {
        int srcn = __shfl(s_w, i, 64);
        float w0 = __shfl(p0, i, 64), w1 = __shfl(p1, i, 64);
        float w2 = __shfl(p2, i, 64), w3 = __shfl(p3, i, 64);
        float w = myhead == 0 ? w0 : myhead == 1 ? w1 : myhead == 2 ? w2 : w3;
        float4 v = *(const float4*)(h + (size_t)srcn * HC + lane * 4);
        facc[0] += v.x * w; facc[1] += v.y * w;
        facc[2] += v.z * w; facc[3] += v.w * w;
      }
    } else {
      // deg > 64: strided two-pass (rare)
      float dn0 = 0.f, dn1 = 0.f, dn2 = 0.f, dn3 = 0.f;
      for (int i = beg + lane; i < end; i += 64) {
        int s = col_src[i];
        float4 a4 = *(const float4*)(as_ + (size_t)s * 4);
        float e0 = a4.x + adv4.x; e0 = e0 > 0.f ? e0 : NEG_SLOPE * e0; dn0 += __expf(e0);
        float e1 = a4.y + adv4.y; e1 = e1 > 0.f ? e1 : NEG_SLOPE * e1; dn1 += __expf(e1);
        float e2 = a4.z + adv4.z; e2 = e2 > 0.f ? e2 : NEG_SLOPE * e2; dn2 += __expf(e2);
        float e3 = a4.w + adv4.w; e3 = e3 > 0.f ? e3 : NEG_SLOPE * e3; dn3 += __expf(e3);
      }
#pragma unroll
      for (int off = 32; off >= 1; off >>= 1) {
        dn0 += __shfl_xor(dn0, off, 64);
        dn1 += __shfl_xor(dn1, off, 64);
        dn2 += __shfl_xor(dn2, off, 64);
        dn3 += __shfl_xor(dn3, off, 64);
      }
      float adm = myhead == 0 ? adv4.x : myhead == 1 ? adv4.y : myhead == 2 ? adv4.z : adv4.w;
      float invdn = 1.f / (myhead == 0 ? dn0 : myhead == 1 ? dn1 : myhead == 2 ? dn2 : dn3);
      invdn *= inv_deg;
      for (int i = beg; i < end; ++i) {
        int s = col_src[i];
        float e = as_[(size_t)s * 4 + myhead] + adm;
        e = (e > 0.f) ? e : NEG_SLOPE * e;
        float w = __expf(e) * invdn;
        float4 v = *(const float4*)(h + (size_t)s * HC + lane * 4);
        facc[0] += v.x * w; facc[1] += v.y * w;
        facc[2] += v.z * w; facc[3] += v.w * w;
      }
    }
  } else {
    // H == 1
    float adv = ad_[node];
    if (deg <= 64) {
      float q = 0.f; int s_w = 0;
      if (lane < deg) {
        s_w = col_src[beg + lane];
        float e = as_[s_w] + adv;
        e = (e > 0.f) ? e : NEG_SLOPE * e;
        q = __expf(e);
      }
      float dn = q;
#pragma unroll
      for (int off = 32; off >= 1; off >>= 1) dn += __shfl_xor(dn, off, 64);
      float qs = q * (1.f / dn) * inv_deg;
      for (int i = 0; i < deg; ++i) {
        int srcn = __shfl(s_w, i, 64);
        float w = __shfl(qs, i, 64);
        facc[0] += h[(size_t)srcn * HC + lane] * w;
      }
    } else {
      float dn = 0.f;
      for (int i = beg + lane; i < end; i += 64) {
        int s = col_src[i];
        float e = as_[s] + adv;
        e = (e > 0.f) ? e : NEG_SLOPE * e;
        dn += __expf(e);
      }
#pragma unroll
      for (int off = 32; off >= 1; off >>= 1) dn += __shfl_xor(dn, off, 64);
      float invdn = (1.f / dn) * inv_deg;
      for (int i = beg; i < end; ++i) {
        int s = col_src[i];
        float e = as_[s] + adv;
        e = (e > 0.f) ? e : NEG_SLOPE * e;
        float w = __expf(e) * invdn;
        facc[0] += h[(size_t)s * HC + lane] * w;
      }
    }
  }

  float* orow = out + (size_t)node * HC + lane * PER;
#pragma unroll
  for (int p = 0; p < PER; ++p) {
    float v = facc[p] + bias[lane * PER + p];
    if (RELU) v = fmaxf(v, 0.f);
    orow[p] = v;
  }
}

// ---------------------------------------------------------------- launcher
extern "C" void kernel_launch(void* const* d_in, const int* in_sizes, int n_in,
                              void* d_out, int out_size, void* d_ws, size_t ws_size,
                              hipStream_t stream) {
  const float* x   = (const float*)d_in[0];
  const int*   ei  = (const int*)d_in[1];
  const float* W0  = (const float*)d_in[2];
  const float* a0s = (const float*)d_in[3];
  const float* a0d = (const float*)d_in[4];
  const float* b0  = (const float*)d_in[5];
  const float* W1  = (const float*)d_in[6];
  const float* a1s = (const float*)d_in[7];
  const float* a1d = (const float*)d_in[8];
  const float* b1  = (const float*)d_in[9];
  const float* W2  = (const float*)d_in[10];
  const float* a2s = (const float*)d_in[11];
  const float* a2d = (const float*)d_in[12];
  const float* b2  = (const float*)d_in[13];

  const int IN = 256;
  const int N = in_sizes[0] / IN;       // 50000
  const int E = in_sizes[1] / 2;        // 600000
  const int Etot = E + N;

  char* ws = (char*)d_ws;
  size_t off = 0;
  auto alloc = [&](size_t bytes) {
    void* p = ws + off;
    off += (bytes + 255) & ~(size_t)255;
    return p;
  };
  float* A       = (float*)alloc((size_t)N * 256 * 4);
  float* Bbuf    = (float*)alloc((size_t)N * 256 * 4);
  float* as_buf  = (float*)alloc((size_t)N * 4 * 4);
  float* ad_buf  = (float*)alloc((size_t)N * 4 * 4);
  int*   row_ptr = (int*)alloc((size_t)(N + 1) * 4);
  int*   cursor  = (int*)alloc((size_t)N * 4);
  int*   cnt     = (int*)alloc((size_t)N * 4);
  int*   col_src = (int*)alloc((size_t)Etot * 4);

  // ---- CSR build ----
  zero_int_kernel<<<(N + 255) / 256, 256, 0, stream>>>(cnt, N);
  count_kernel<<<(Etot + 255) / 256, 256, 0, stream>>>(ei, E, N, cnt);
  scan_kernel<<<1, 1024, 0, stream>>>(cnt, row_ptr, cursor, N);
  fill_kernel<<<(Etot + 255) / 256, 256, 0, stream>>>(ei, E, N, cursor, col_src);

  dim3 g0(256 / 128, (N + 127) / 128);
  dim3 g2(64 / 64, (N + 127) / 128);
  int node_blocks = (N + 3) / 4;

  // ---- layer 0 ----
  sgemm_kernel<128, 128><<<g0, 256, 0, stream>>>(x, W0, A, N, 256, 256);
  alpha_kernel<4, 64><<<node_blocks, 256, 0, stream>>>(A, a0s, a0d, as_buf, ad_buf, N);
  aggregate_kernel<4, 64, true><<<node_blocks, 256, 0, stream>>>(
      A, as_buf, ad_buf, row_ptr, col_src, b0, Bbuf, N);

  // ---- layer 1 ----
  sgemm_kernel<128, 128><<<g0, 256, 0, stream>>>(Bbuf, W1, A, N, 256, 256);
  alpha_kernel<4, 64><<<node_blocks, 256, 0, stream>>>(A, a1s, a1d, as_buf, ad_buf, N);
  aggregate_kernel<4, 64, true><<<node_blocks, 256, 0, stream>>>(
      A, as_buf, ad_buf, row_ptr, col_src, b1, Bbuf, N);

  // ---- layer 2 ----
  sgemm_kernel<128, 64><<<g2, 256, 0, stream>>>(Bbuf, W2, A, N, 64, 256);
  alpha_kernel<1, 64><<<node_blocks, 256, 0, stream>>>(A, a2s, a2d, as_buf, ad_buf, N);
  aggregate_kernel<1, 64, false><<<node_blocks, 256, 0, stream>>>(
      A, as_buf, ad_buf, row_ptr, col_src, b2, (float*)d_out, N);
}

// Round 5
// 769.328 us; speedup vs baseline: 1.2101x; 1.2101x over previous
//
#include <hip/hip_runtime.h>

#define NEG_SLOPE 0.2f

// ---------------------------------------------------------------- CSR build
__global__ void zero_int_kernel(int* __restrict__ p, int n) {
  int i = blockIdx.x * blockDim.x + threadIdx.x;
  if (i < n) p[i] = 0;
}

__global__ void count_kernel(const int* __restrict__ ei, int E, int N,
                             int* __restrict__ cnt) {
  int e = blockIdx.x * blockDim.x + threadIdx.x;
  int tot = E + N;
  if (e >= tot) return;
  int dst = (e < E) ? ei[E + e] : (e - E);
  atomicAdd(&cnt[dst], 1);
}

// 1024 threads, one block. Per-thread serial chunk + shuffle block-scan.
__global__ __launch_bounds__(1024) void scan_kernel(const int* __restrict__ cnt,
                                                    int* __restrict__ row_ptr,
                                                    int* __restrict__ cursor,
                                                    int N) {
  int t = threadIdx.x;
  int CH = (N + 1023) >> 10;
  int b = t * CH; if (b > N) b = N;
  int e = b + CH; if (e > N) e = N;
  int sum = 0;
  for (int i = b; i < e; ++i) sum += cnt[i];
  int lane = t & 63, wid = t >> 6;
  int v = sum;
#pragma unroll
  for (int off = 1; off < 64; off <<= 1) {
    int u = __shfl_up(v, off, 64);
    if (lane >= off) v += u;
  }
  __shared__ int wsum[16];
  __shared__ int wpre[16];
  if (lane == 63) wsum[wid] = v;
  __syncthreads();
  if (t < 16) {
    int wv = wsum[t];
#pragma unroll
    for (int off = 1; off < 16; off <<= 1) {
      int u = __shfl_up(wv, off, 16);
      if (t >= off) wv += u;
    }
    wpre[t] = wv - wsum[t];
  }
  __syncthreads();
  int run = wpre[wid] + (v - sum);
  for (int i = b; i < e; ++i) {
    int c = cnt[i];
    row_ptr[i] = run;
    cursor[i] = run;
    run += c;
  }
  if (t == 1023) row_ptr[N] = run;
}

__global__ void fill_kernel(const int* __restrict__ ei, int E, int N,
                            int* __restrict__ cursor, int* __restrict__ col_src) {
  int e = blockIdx.x * blockDim.x + threadIdx.x;
  int tot = E + N;
  if (e >= tot) return;
  int src, dst;
  if (e < E) { src = ei[e]; dst = ei[E + e]; } else { src = e - E; dst = e - E; }
  int pos = atomicAdd(&cursor[dst], 1);
  col_src[pos] = src;
}

// ---------------------------------------------------------------- SGEMM fp32
// Y[M,N] = X[M,K] @ W[K,N].  256 threads, BK=16.  (round-2 proven: 117 us)
// BM=128 always. BN=128: 8x8 microtile split into 4+4 halves. BN=64: 8x4.
template <int BM, int BN>
__global__ __launch_bounds__(256) void sgemm_kernel(const float* __restrict__ X,
                                                    const float* __restrict__ W,
                                                    float* __restrict__ Y,
                                                    int M, int N, int K) {
  constexpr int BK = 16;
  constexpr int LDA = BM + 4;
  constexpr int HM = BM / 2;
  constexpr int JH = (BN == 128) ? 2 : 1;
  constexpr int HN = BN / 2;
  __shared__ float As[BK][LDA];
  __shared__ float Bs[BK][BN];
  int tid = threadIdx.x;
  int br = blockIdx.y * BM, bc = blockIdx.x * BN;
  int trow = tid >> 4, tcol = tid & 15;
  float acc[2][JH][4][4] = {};
  constexpr int nA4 = BM * BK / 1024;
  constexpr int nB4 = BK * BN / 1024;
  for (int k0 = 0; k0 < K; k0 += BK) {
#pragma unroll
    for (int i = 0; i < nA4; ++i) {
      int f = tid + i * 256;
      int row = f >> 2;
      int kq = (f & 3) * 4;
      int gm = br + row;
      float4 v = make_float4(0.f, 0.f, 0.f, 0.f);
      if (gm < M) v = *(const float4*)&X[(size_t)gm * K + k0 + kq];
      As[kq + 0][row] = v.x; As[kq + 1][row] = v.y;
      As[kq + 2][row] = v.z; As[kq + 3][row] = v.w;
    }
#pragma unroll
    for (int i = 0; i < nB4; ++i) {
      int f = tid + i * 256;
      int kk = f / (BN / 4);
      int nq = (f % (BN / 4)) * 4;
      *(float4*)&Bs[kk][nq] = *(const float4*)&W[(size_t)(k0 + kk) * N + bc + nq];
    }
    __syncthreads();
#pragma unroll
    for (int kk = 0; kk < BK; ++kk) {
      float ar[2][4], brg[JH][4];
      *(float4*)&ar[0][0] = *(const float4*)&As[kk][trow * 4];
      *(float4*)&ar[1][0] = *(const float4*)&As[kk][trow * 4 + HM];
      *(float4*)&brg[0][0] = *(const float4*)&Bs[kk][tcol * 4];
      if constexpr (JH == 2)
        *(float4*)&brg[1][0] = *(const float4*)&Bs[kk][tcol * 4 + HN];
#pragma unroll
      for (int ih = 0; ih < 2; ++ih)
#pragma unroll
        for (int jh = 0; jh < JH; ++jh)
#pragma unroll
          for (int i = 0; i < 4; ++i)
#pragma unroll
            for (int j = 0; j < 4; ++j)
              acc[ih][jh][i][j] += ar[ih][i] * brg[jh][j];
    }
    __syncthreads();
  }
#pragma unroll
  for (int ih = 0; ih < 2; ++ih)
#pragma unroll
    for (int i = 0; i < 4; ++i) {
      int gm = br + ih * HM + trow * 4 + i;
      if (gm >= M) continue;
#pragma unroll
      for (int jh = 0; jh < JH; ++jh) {
        float4 o = make_float4(acc[ih][jh][i][0], acc[ih][jh][i][1],
                               acc[ih][jh][i][2], acc[ih][jh][i][3]);
        int gn = bc + (JH == 2 ? jh * HN : 0) + tcol * 4;
        *(float4*)&Y[(size_t)gm * N + gn] = o;
      }
    }
}

// ------------------------------------------------- per-node alpha_s/alpha_d
template <int H, int C>
__global__ void alpha_kernel(const float* __restrict__ h,
                             const float* __restrict__ a_s,
                             const float* __restrict__ a_d,
                             float* __restrict__ out_s,
                             float* __restrict__ out_d, int N) {
  constexpr int HC = H * C;
  constexpr int PER = HC / 64;
  constexpr int SEG = C / PER;
  int lane = threadIdx.x & 63;
  int node = (blockIdx.x * blockDim.x + threadIdx.x) >> 6;
  if (node >= N) return;
  int cbase = lane * PER;
  const float* row = h + (size_t)node * HC + cbase;
  float ss, dd;
  if constexpr (PER == 4) {
    float4 v = *(const float4*)row;
    float4 s4 = *(const float4*)(a_s + cbase);
    float4 d4 = *(const float4*)(a_d + cbase);
    ss = v.x * s4.x + v.y * s4.y + v.z * s4.z + v.w * s4.w;
    dd = v.x * d4.x + v.y * d4.y + v.z * d4.z + v.w * d4.w;
  } else {
    float v = row[0];
    ss = v * a_s[cbase];
    dd = v * a_d[cbase];
  }
#pragma unroll
  for (int off = SEG >> 1; off >= 1; off >>= 1) {
    ss += __shfl_xor(ss, off, 64);
    dd += __shfl_xor(dd, off, 64);
  }
  if ((lane % SEG) == 0) {
    int head = lane / SEG;
    out_s[(size_t)node * H + head] = ss;
    out_d[(size_t)node * H + head] = dd;
  }
}

// ------------------------------- segment softmax + mean-aggregate + bias(+relu)
// One wave per dst node. Gather loops unrolled x4 -> 4 loads in flight.
// NOTE: __shfl(expr, i) evaluates expr on the SOURCE lane — any head-dependent
// select must happen AFTER the shuffle (round-4 bug).
template <int H, int C, bool RELU>
__global__ void aggregate_kernel(const float* __restrict__ h,
                                 const float* __restrict__ as_,
                                 const float* __restrict__ ad_,
                                 const int* __restrict__ row_ptr,
                                 const int* __restrict__ col_src,
                                 const float* __restrict__ bias,
                                 float* __restrict__ out, int N) {
  constexpr int HC = H * C;
  constexpr int PER = HC / 64;
  int lane = threadIdx.x & 63;
  int node = (blockIdx.x * blockDim.x + threadIdx.x) >> 6;
  if (node >= N) return;
  int beg = row_ptr[node], end = row_ptr[node + 1];
  int deg = end - beg;
  float inv_deg = 1.f / (float)deg;
  int myhead = (lane * PER) / C;
  float facc[PER] = {};

  if constexpr (H == 4) {
    float4 adv4 = *(const float4*)(ad_ + (size_t)node * 4);
    const float* hl = h + lane * 4;
    if (deg <= 16) {
      // lane = head_w*16 + e_w holds weight of edge e_w for head head_w;
      // consumer reads from its own head group -> single shfl, already correct.
      int head_w = lane >> 4, e_w = lane & 15;
      float q = 0.f; int s_w = 0;
      if (e_w < deg) {
        s_w = col_src[beg + e_w];
        float4 a4 = *(const float4*)(as_ + (size_t)s_w * 4);
        float av = head_w == 0 ? a4.x : head_w == 1 ? a4.y : head_w == 2 ? a4.z : a4.w;
        float dv = head_w == 0 ? adv4.x : head_w == 1 ? adv4.y : head_w == 2 ? adv4.z : adv4.w;
        float e = av + dv;
        e = (e > 0.f) ? e : NEG_SLOPE * e;
        q = __expf(e);
      }
      float dn = q;
      dn += __shfl_xor(dn, 1, 64);
      dn += __shfl_xor(dn, 2, 64);
      dn += __shfl_xor(dn, 4, 64);
      dn += __shfl_xor(dn, 8, 64);
      float qs = q * (1.f / dn) * inv_deg;
      int base = myhead << 4;
      int i = 0;
      for (; i + 4 <= deg; i += 4) {
        int s0 = __shfl(s_w, base + i + 0, 64);
        int s1 = __shfl(s_w, base + i + 1, 64);
        int s2 = __shfl(s_w, base + i + 2, 64);
        int s3 = __shfl(s_w, base + i + 3, 64);
        float w0 = __shfl(qs, base + i + 0, 64);
        float w1 = __shfl(qs, base + i + 1, 64);
        float w2 = __shfl(qs, base + i + 2, 64);
        float w3 = __shfl(qs, base + i + 3, 64);
        float4 v0 = *(const float4*)(hl + (size_t)s0 * HC);
        float4 v1 = *(const float4*)(hl + (size_t)s1 * HC);
        float4 v2 = *(const float4*)(hl + (size_t)s2 * HC);
        float4 v3 = *(const float4*)(hl + (size_t)s3 * HC);
        facc[0] += v0.x * w0; facc[1] += v0.y * w0; facc[2] += v0.z * w0; facc[3] += v0.w * w0;
        facc[0] += v1.x * w1; facc[1] += v1.y * w1; facc[2] += v1.z * w1; facc[3] += v1.w * w1;
        facc[0] += v2.x * w2; facc[1] += v2.y * w2; facc[2] += v2.z * w2; facc[3] += v2.w * w2;
        facc[0] += v3.x * w3; facc[1] += v3.y * w3; facc[2] += v3.z * w3; facc[3] += v3.w * w3;
      }
      for (; i < deg; ++i) {
        int srcn = __shfl(s_w, base + i, 64);
        float w = __shfl(qs, base + i, 64);
        float4 v = *(const float4*)(hl + (size_t)srcn * HC);
        facc[0] += v.x * w; facc[1] += v.y * w; facc[2] += v.z * w; facc[3] += v.w * w;
      }
    } else if (deg <= 64) {
      float p0 = 0.f, p1 = 0.f, p2 = 0.f, p3 = 0.f; int s_w = 0;
      if (lane < deg) {
        s_w = col_src[beg + lane];
        float4 a4 = *(const float4*)(as_ + (size_t)s_w * 4);
        float e0 = a4.x + adv4.x; e0 = e0 > 0.f ? e0 : NEG_SLOPE * e0; p0 = __expf(e0);
        float e1 = a4.y + adv4.y; e1 = e1 > 0.f ? e1 : NEG_SLOPE * e1; p1 = __expf(e1);
        float e2 = a4.z + adv4.z; e2 = e2 > 0.f ? e2 : NEG_SLOPE * e2; p2 = __expf(e2);
        float e3 = a4.w + adv4.w; e3 = e3 > 0.f ? e3 : NEG_SLOPE * e3; p3 = __expf(e3);
      }
      float d0 = p0, d1 = p1, d2 = p2, d3 = p3;
#pragma unroll
      for (int off = 32; off >= 1; off >>= 1) {
        d0 += __shfl_xor(d0, off, 64);
        d1 += __shfl_xor(d1, off, 64);
        d2 += __shfl_xor(d2, off, 64);
        d3 += __shfl_xor(d3, off, 64);
      }
      p0 *= (1.f / d0) * inv_deg;
      p1 *= (1.f / d1) * inv_deg;
      p2 *= (1.f / d2) * inv_deg;
      p3 *= (1.f / d3) * inv_deg;
      int i = 0;
      for (; i + 2 <= deg; i += 2) {
        int s0 = __shfl(s_w, i + 0, 64);
        int s1 = __shfl(s_w, i + 1, 64);
        // broadcast ALL heads, select by reader's head after the shuffle
        float a00 = __shfl(p0, i + 0, 64), a01 = __shfl(p1, i + 0, 64);
        float a02 = __shfl(p2, i + 0, 64), a03 = __shfl(p3, i + 0, 64);
        float a10 = __shfl(p0, i + 1, 64), a11 = __shfl(p1, i + 1, 64);
        float a12 = __shfl(p2, i + 1, 64), a13 = __shfl(p3, i + 1, 64);
        float w0 = myhead == 0 ? a00 : myhead == 1 ? a01 : myhead == 2 ? a02 : a03;
        float w1 = myhead == 0 ? a10 : myhead == 1 ? a11 : myhead == 2 ? a12 : a13;
        float4 v0 = *(const float4*)(hl + (size_t)s0 * HC);
        float4 v1 = *(const float4*)(hl + (size_t)s1 * HC);
        facc[0] += v0.x * w0; facc[1] += v0.y * w0; facc[2] += v0.z * w0; facc[3] += v0.w * w0;
        facc[0] += v1.x * w1; facc[1] += v1.y * w1; facc[2] += v1.z * w1; facc[3] += v1.w * w1;
      }
      for (; i < deg; ++i) {
        int srcn = __shfl(s_w, i, 64);
        float b0 = __shfl(p0, i, 64), b1 = __shfl(p1, i, 64);
        float b2 = __shfl(p2, i, 64), b3 = __shfl(p3, i, 64);
        float w = myhead == 0 ? b0 : myhead == 1 ? b1 : myhead == 2 ? b2 : b3;
        float4 v = *(const float4*)(hl + (size_t)srcn * HC);
        facc[0] += v.x * w; facc[1] += v.y * w; facc[2] += v.z * w; facc[3] += v.w * w;
      }
    } else {
      // deg > 64: strided two-pass (rare)
      float dn0 = 0.f, dn1 = 0.f, dn2 = 0.f, dn3 = 0.f;
      for (int i = beg + lane; i < end; i += 64) {
        int s = col_src[i];
        float4 a4 = *(const float4*)(as_ + (size_t)s * 4);
        float e0 = a4.x + adv4.x; e0 = e0 > 0.f ? e0 : NEG_SLOPE * e0; dn0 += __expf(e0);
        float e1 = a4.y + adv4.y; e1 = e1 > 0.f ? e1 : NEG_SLOPE * e1; dn1 += __expf(e1);
        float e2 = a4.z + adv4.z; e2 = e2 > 0.f ? e2 : NEG_SLOPE * e2; dn2 += __expf(e2);
        float e3 = a4.w + adv4.w; e3 = e3 > 0.f ? e3 : NEG_SLOPE * e3; dn3 += __expf(e3);
      }
#pragma unroll
      for (int off = 32; off >= 1; off >>= 1) {
        dn0 += __shfl_xor(dn0, off, 64);
        dn1 += __shfl_xor(dn1, off, 64);
        dn2 += __shfl_xor(dn2, off, 64);
        dn3 += __shfl_xor(dn3, off, 64);
      }
      float adm = myhead == 0 ? adv4.x : myhead == 1 ? adv4.y : myhead == 2 ? adv4.z : adv4.w;
      float invdn = 1.f / (myhead == 0 ? dn0 : myhead == 1 ? dn1 : myhead == 2 ? dn2 : dn3);
      invdn *= inv_deg;
      for (int i = beg; i < end; ++i) {
        int s = col_src[i];
        float e = as_[(size_t)s * 4 + myhead] + adm;
        e = (e > 0.f) ? e : NEG_SLOPE * e;
        float w = __expf(e) * invdn;
        float4 v = *(const float4*)(hl + (size_t)s * HC);
        facc[0] += v.x * w; facc[1] += v.y * w; facc[2] += v.z * w; facc[3] += v.w * w;
      }
    }
  } else {
    // H == 1
    float adv = ad_[node];
    const float* hl = h + lane;
    if (deg <= 64) {
      float q = 0.f; int s_w = 0;
      if (lane < deg) {
        s_w = col_src[beg + lane];
        float e = as_[s_w] + adv;
        e = (e > 0.f) ? e : NEG_SLOPE * e;
        q = __expf(e);
      }
      float dn = q;
#pragma unroll
      for (int off = 32; off >= 1; off >>= 1) dn += __shfl_xor(dn, off, 64);
      float qs = q * (1.f / dn) * inv_deg;
      int i = 0;
      for (; i + 4 <= deg; i += 4) {
        int s0 = __shfl(s_w, i + 0, 64);
        int s1 = __shfl(s_w, i + 1, 64);
        int s2 = __shfl(s_w, i + 2, 64);
        int s3 = __shfl(s_w, i + 3, 64);
        float w0 = __shfl(qs, i + 0, 64);
        float w1 = __shfl(qs, i + 1, 64);
        float w2 = __shfl(qs, i + 2, 64);
        float w3 = __shfl(qs, i + 3, 64);
        float v0 = hl[(size_t)s0 * HC];
        float v1 = hl[(size_t)s1 * HC];
        float v2 = hl[(size_t)s2 * HC];
        float v3 = hl[(size_t)s3 * HC];
        facc[0] += v0 * w0; facc[0] += v1 * w1;
        facc[0] += v2 * w2; facc[0] += v3 * w3;
      }
      for (; i < deg; ++i) {
        int srcn = __shfl(s_w, i, 64);
        float w = __shfl(qs, i, 64);
        facc[0] += hl[(size_t)srcn * HC] * w;
      }
    } else {
      float dn = 0.f;
      for (int i = beg + lane; i < end; i += 64) {
        int s = col_src[i];
        float e = as_[s] + adv;
        e = (e > 0.f) ? e : NEG_SLOPE * e;
        dn += __expf(e);
      }
#pragma unroll
      for (int off = 32; off >= 1; off >>= 1) dn += __shfl_xor(dn, off, 64);
      float invdn = (1.f / dn) * inv_deg;
      for (int i = beg; i < end; ++i) {
        int s = col_src[i];
        float e = as_[s] + adv;
        e = (e > 0.f) ? e : NEG_SLOPE * e;
        float w = __expf(e) * invdn;
        facc[0] += hl[(size_t)s * HC] * w;
      }
    }
  }

  float* orow = out + (size_t)node * HC + lane * PER;
#pragma unroll
  for (int p = 0; p < PER; ++p) {
    float v = facc[p] + bias[lane * PER + p];
    if (RELU) v = fmaxf(v, 0.f);
    orow[p] = v;
  }
}

// ---------------------------------------------------------------- launcher
extern "C" void kernel_launch(void* const* d_in, const int* in_sizes, int n_in,
                              void* d_out, int out_size, void* d_ws, size_t ws_size,
                              hipStream_t stream) {
  const float* x   = (const float*)d_in[0];
  const int*   ei  = (const int*)d_in[1];
  const float* W0  = (const float*)d_in[2];
  const float* a0s = (const float*)d_in[3];
  const float* a0d = (const float*)d_in[4];
  const float* b0  = (const float*)d_in[5];
  const float* W1  = (const float*)d_in[6];
  const float* a1s = (const float*)d_in[7];
  const float* a1d = (const float*)d_in[8];
  const float* b1  = (const float*)d_in[9];
  const float* W2  = (const float*)d_in[10];
  const float* a2s = (const float*)d_in[11];
  const float* a2d = (const float*)d_in[12];
  const float* b2  = (const float*)d_in[13];

  const int IN = 256;
  const int N = in_sizes[0] / IN;       // 50000
  const int E = in_sizes[1] / 2;        // 600000
  const int Etot = E + N;

  char* ws = (char*)d_ws;
  size_t off = 0;
  auto alloc = [&](size_t bytes) {
    void* p = ws + off;
    off += (bytes + 255) & ~(size_t)255;
    return p;
  };
  float* A       = (float*)alloc((size_t)N * 256 * 4);
  float* Bbuf    = (float*)alloc((size_t)N * 256 * 4);
  float* as_buf  = (float*)alloc((size_t)N * 4 * 4);
  float* ad_buf  = (float*)alloc((size_t)N * 4 * 4);
  int*   row_ptr = (int*)alloc((size_t)(N + 1) * 4);
  int*   cursor  = (int*)alloc((size_t)N * 4);
  int*   cnt     = (int*)alloc((size_t)N * 4);
  int*   col_src = (int*)alloc((size_t)Etot * 4);

  // ---- CSR build ----
  zero_int_kernel<<<(N + 255) / 256, 256, 0, stream>>>(cnt, N);
  count_kernel<<<(Etot + 255) / 256, 256, 0, stream>>>(ei, E, N, cnt);
  scan_kernel<<<1, 1024, 0, stream>>>(cnt, row_ptr, cursor, N);
  fill_kernel<<<(Etot + 255) / 256, 256, 0, stream>>>(ei, E, N, cursor, col_src);

  dim3 g0(256 / 128, (N + 127) / 128);  // 2 x 391
  dim3 g2(64 / 64, (N + 127) / 128);    // 1 x 391
  int node_blocks = (N + 3) / 4;

  // ---- layer 0 ----
  sgemm_kernel<128, 128><<<g0, 256, 0, stream>>>(x, W0, A, N, 256, 256);
  alpha_kernel<4, 64><<<node_blocks, 256, 0, stream>>>(A, a0s, a0d, as_buf, ad_buf, N);
  aggregate_kernel<4, 64, true><<<node_blocks, 256, 0, stream>>>(
      A, as_buf, ad_buf, row_ptr, col_src, b0, Bbuf, N);

  // ---- layer 1 ----
  sgemm_kernel<128, 128><<<g0, 256, 0, stream>>>(Bbuf, W1, A, N, 256, 256);
  alpha_kernel<4, 64><<<node_blocks, 256, 0, stream>>>(A, a1s, a1d, as_buf, ad_buf, N);
  aggregate_kernel<4, 64, true><<<node_blocks, 256, 0, stream>>>(
      A, as_buf, ad_buf, row_ptr, col_src, b1, Bbuf, N);

  // ---- layer 2 ----
  sgemm_kernel<128, 64><<<g2, 256, 0, stream>>>(Bbuf, W2, A, N, 64, 256);
  alpha_kernel<1, 64><<<node_blocks, 256, 0, stream>>>(A, a2s, a2d, as_buf, ad_buf, N);
  aggregate_kernel<1, 64, false><<<node_blocks, 256, 0, stream>>>(
      A, as_buf, ad_buf, row_ptr, col_src, b2, (float*)d_out, N);
}